// Round 1
// baseline (554.130 us; speedup 1.0000x reference)
//
#include <hip/hip_runtime.h>
#include <hip/hip_bf16.h>
#include <stdint.h>

#define NUM_EXPERTS 32
#define HIDDEN 2048
#define INTER 2816
#define HALFI 1408
#define TOKENS 1024
#define TOPK 8
#define TA (TOKENS*TOPK)
#define CAP 512
#define BK 64

typedef float f32x4 __attribute__((ext_vector_type(4)));
typedef __bf16 bf16x8 __attribute__((ext_vector_type(8)));

__device__ __forceinline__ uint32_t swz(uint32_t row, uint32_t colbyte) {
  // 128-byte rows; XOR row bits into byte bits 4-6 -> conflict-free-ish ds_read_b128
  return row * 128u + (colbyte ^ ((row & 7u) << 4));
}
__device__ __forceinline__ uint32_t pk2(float a, float b) {
  union { __bf16 h[2]; uint32_t u; } c;
  c.h[0] = (__bf16)a; c.h[1] = (__bf16)b; return c.u;
}
__device__ __forceinline__ uint16_t bf16b(float a) {
  union { __bf16 h; uint16_t u; } c; c.h = (__bf16)a; return c.u;
}

// ---------------- routing ----------------
__global__ void route_count(const int* __restrict__ tkidx, int* __restrict__ offs) {
  __shared__ int cnt[NUM_EXPERTS];
  int tid = threadIdx.x;
  if (tid < NUM_EXPERTS) cnt[tid] = 0;
  __syncthreads();
  for (int i = tid; i < TA; i += 256) atomicAdd(&cnt[tkidx[i]], 1);
  __syncthreads();
  if (tid == 0) {
    int acc = 0;
    for (int e = 0; e < NUM_EXPERTS; ++e) { offs[e] = acc; acc += cnt[e]; }
    offs[NUM_EXPERTS] = acc;
  }
}

// one wave per expert; stable rank via ballot
__global__ void route_build(const int* __restrict__ tkidx, const float* __restrict__ tkw,
                            const int* __restrict__ offs,
                            int* __restrict__ tok_of_row, float* __restrict__ w_of_row) {
  int e = blockIdx.x;
  int lane = threadIdx.x;
  int base = offs[e];
  int run = 0;
  for (int c0 = 0; c0 < TA; c0 += 64) {
    int i = c0 + lane;
    bool p = (tkidx[i] == e);
    unsigned long long m = __ballot(p);
    if (p) {
      int rank = run + __popcll(m & ((1ull << lane) - 1ull));
      if (rank < CAP) {
        tok_of_row[base + rank] = i >> 3;   // TOPK = 8
        w_of_row[base + rank]   = tkw[i];
      }
    }
    run += __popcll(m);
  }
}

// ---------------- GEMM1: h = X * W1^T, a = silu(gate)*up -> A_ws (bf16) ----------------
__global__ __launch_bounds__(256, 2) void moe_gemm1(
    const float* __restrict__ hidden, const float* __restrict__ w1,
    const int* __restrict__ offs, const int* __restrict__ tok_of_row,
    uint16_t* __restrict__ A_ws)
{
  const int e = blockIdx.z, mt = blockIdx.y, ns = blockIdx.x;
  const int off = offs[e];
  const int cnt = min(offs[e + 1] - off, CAP);
  if (mt * 128 >= cnt) return;

  __shared__ __align__(16) char lds[65536];   // A:2x16KB  B:2x16KB
  const int tid = threadIdx.x;
  const int tr = tid >> 4, c4 = tid & 15;

  // A (tokens) row sources: row = j*16+tr, 4 floats at col c4*4
  const float* aptr[8];
  uint32_t wa[8];
#pragma unroll
  for (int j = 0; j < 8; ++j) {
    int row = j * 16 + tr;
    int grow = mt * 128 + row;
    aptr[j] = (grow < cnt) ? (hidden + (size_t)tok_of_row[off + grow] * HIDDEN + c4 * 4) : nullptr;
    wa[j] = swz(row, (uint32_t)c4 * 8);
  }
  // B rows: 0..63 = gate cols ns*64+row ; 64..127 = up cols 1408+ns*64+(row-64)
  const float* bbase_g = w1 + ((size_t)e * INTER + ns * 64 + tr) * HIDDEN + c4 * 4;
  const float* bbase_u = w1 + ((size_t)e * INTER + HALFI + ns * 64 + tr) * HIDDEN + c4 * 4;
  uint32_t wb[8];
#pragma unroll
  for (int j = 0; j < 8; ++j) wb[j] = swz((uint32_t)(j * 16 + tr), (uint32_t)c4 * 8);

  f32x4 ra[8], rb[8];

  const int lane = tid & 63, wv = tid >> 6;
  const int wm = wv * 32;
  const int fr = lane & 15, fq = lane >> 4;

  f32x4 acc[2][8];
#pragma unroll
  for (int i = 0; i < 2; ++i)
#pragma unroll
    for (int j = 0; j < 8; ++j) acc[i][j] = (f32x4)0.f;

  auto LOAD = [&](int k0) {
#pragma unroll
    for (int j = 0; j < 8; ++j)
      ra[j] = aptr[j] ? *(const f32x4*)(aptr[j] + k0) : (f32x4)0.f;
#pragma unroll
    for (int j = 0; j < 4; ++j)
      rb[j] = *(const f32x4*)(bbase_g + (size_t)j * 16 * HIDDEN + k0);
#pragma unroll
    for (int j = 0; j < 4; ++j)
      rb[4 + j] = *(const f32x4*)(bbase_u + (size_t)j * 16 * HIDDEN + k0);
  };
  auto WRITE = [&](int buf) {
    char* pa = lds + buf * 16384;
    char* pb = lds + 32768 + buf * 16384;
#pragma unroll
    for (int j = 0; j < 8; ++j) {
      uint2 v; v.x = pk2(ra[j].x, ra[j].y); v.y = pk2(ra[j].z, ra[j].w);
      *(uint2*)(pa + wa[j]) = v;
    }
#pragma unroll
    for (int j = 0; j < 8; ++j) {
      uint2 v; v.x = pk2(rb[j].x, rb[j].y); v.y = pk2(rb[j].z, rb[j].w);
      *(uint2*)(pb + wb[j]) = v;
    }
  };

  const int NT = HIDDEN / BK;  // 32
  LOAD(0); WRITE(0);
  int cur = 0;
  for (int t = 0; t < NT; ++t) {
    __syncthreads();                       // buf[cur] visible; prior reads drained
    if (t + 1 < NT) LOAD((t + 1) * BK);    // issue prefetch; latency hides under MFMA
    const char* pa = lds + cur * 16384;
    const char* pb = lds + 32768 + cur * 16384;
#pragma unroll
    for (int ks = 0; ks < 2; ++ks) {
      const uint32_t kb = (uint32_t)(ks * 64 + fq * 16);
      bf16x8 af[2], bfv[8];
#pragma unroll
      for (int mf = 0; mf < 2; ++mf)
        af[mf] = *(const bf16x8*)(pa + swz((uint32_t)(wm + mf * 16 + fr), kb));
#pragma unroll
      for (int nf = 0; nf < 8; ++nf)
        bfv[nf] = *(const bf16x8*)(pb + swz((uint32_t)(nf * 16 + fr), kb));
#pragma unroll
      for (int mf = 0; mf < 2; ++mf)
#pragma unroll
        for (int nf = 0; nf < 8; ++nf)
          acc[mf][nf] = __builtin_amdgcn_mfma_f32_16x16x32_bf16(af[mf], bfv[nf], acc[mf][nf], 0, 0, 0);
    }
    if (t + 1 < NT) WRITE(cur ^ 1);
    cur ^= 1;
  }

  // epilogue: silu(gate)*up -> bf16 A_ws
#pragma unroll
  for (int mf = 0; mf < 2; ++mf) {
#pragma unroll
    for (int r = 0; r < 4; ++r) {
      int grow = mt * 128 + wm + mf * 16 + fq * 4 + r;
      if (grow < cnt) {
        size_t s = (size_t)(off + grow);
#pragma unroll
        for (int nf = 0; nf < 4; ++nf) {
          float g = acc[mf][nf][r];
          float u = acc[mf][nf + 4][r];
          float val = g / (1.f + __expf(-g)) * u;
          A_ws[s * HALFI + ns * 64 + nf * 16 + fr] = bf16b(val);
        }
      }
    }
  }
}

// ---------------- GEMM2: out = (A * W2^T) * w, scatter-add ----------------
__global__ __launch_bounds__(256, 2) void moe_gemm2(
    const uint16_t* __restrict__ A_ws, const float* __restrict__ w2,
    const int* __restrict__ offs, const int* __restrict__ tok_of_row,
    const float* __restrict__ w_of_row, float* __restrict__ out)
{
  const int e = blockIdx.z, mt = blockIdx.y, ns = blockIdx.x;
  const int off = offs[e];
  const int cnt = min(offs[e + 1] - off, CAP);
  if (mt * 128 >= cnt) return;

  __shared__ __align__(16) char lds[65536];
  const int tid = threadIdx.x;

  // A staging (bf16 passthrough): row = j*32 + (tid>>3), 8 elems at col (tid&7)*8
  const int ar = tid >> 3, c8 = tid & 7;
  const uint16_t* aptr[4];
  uint32_t wa[4];
#pragma unroll
  for (int j = 0; j < 4; ++j) {
    int row = j * 32 + ar;
    int grow = mt * 128 + row;
    aptr[j] = (grow < cnt) ? (A_ws + (size_t)(off + grow) * HALFI + c8 * 8) : nullptr;
    wa[j] = swz((uint32_t)row, (uint32_t)c8 * 16);
  }
  // B staging (fp32->bf16): rows = out cols m2 = ns*128 + j*16+tr
  const int tr = tid >> 4, c4 = tid & 15;
  const float* bbase = w2 + ((size_t)e * HIDDEN + ns * 128 + tr) * HALFI + c4 * 4;
  uint32_t wb[8];
#pragma unroll
  for (int j = 0; j < 8; ++j) wb[j] = swz((uint32_t)(j * 16 + tr), (uint32_t)c4 * 8);

  uint4 raw[4]; f32x4 rb[8];

  const int lane = tid & 63, wv = tid >> 6;
  const int wm = wv * 32;
  const int fr = lane & 15, fq = lane >> 4;

  f32x4 acc[2][8];
#pragma unroll
  for (int i = 0; i < 2; ++i)
#pragma unroll
    for (int j = 0; j < 8; ++j) acc[i][j] = (f32x4)0.f;

  auto LOAD = [&](int k0) {
#pragma unroll
    for (int j = 0; j < 4; ++j)
      raw[j] = aptr[j] ? *(const uint4*)(aptr[j] + k0) : make_uint4(0, 0, 0, 0);
#pragma unroll
    for (int j = 0; j < 8; ++j)
      rb[j] = *(const f32x4*)(bbase + (size_t)j * 16 * HALFI + k0);
  };
  auto WRITE = [&](int buf) {
    char* pa = lds + buf * 16384;
    char* pb = lds + 32768 + buf * 16384;
#pragma unroll
    for (int j = 0; j < 4; ++j) *(uint4*)(pa + wa[j]) = raw[j];
#pragma unroll
    for (int j = 0; j < 8; ++j) {
      uint2 v; v.x = pk2(rb[j].x, rb[j].y); v.y = pk2(rb[j].z, rb[j].w);
      *(uint2*)(pb + wb[j]) = v;
    }
  };

  const int NT = HALFI / BK;  // 22
  LOAD(0); WRITE(0);
  int cur = 0;
  for (int t = 0; t < NT; ++t) {
    __syncthreads();
    if (t + 1 < NT) LOAD((t + 1) * BK);
    const char* pa = lds + cur * 16384;
    const char* pb = lds + 32768 + cur * 16384;
#pragma unroll
    for (int ks = 0; ks < 2; ++ks) {
      const uint32_t kb = (uint32_t)(ks * 64 + fq * 16);
      bf16x8 af[2], bfv[8];
#pragma unroll
      for (int mf = 0; mf < 2; ++mf)
        af[mf] = *(const bf16x8*)(pa + swz((uint32_t)(wm + mf * 16 + fr), kb));
#pragma unroll
      for (int nf = 0; nf < 8; ++nf)
        bfv[nf] = *(const bf16x8*)(pb + swz((uint32_t)(nf * 16 + fr), kb));
#pragma unroll
      for (int mf = 0; mf < 2; ++mf)
#pragma unroll
        for (int nf = 0; nf < 8; ++nf)
          acc[mf][nf] = __builtin_amdgcn_mfma_f32_16x16x32_bf16(af[mf], bfv[nf], acc[mf][nf], 0, 0, 0);
    }
    if (t + 1 < NT) WRITE(cur ^ 1);
    cur ^= 1;
  }

  // epilogue: weighted scatter-add to token rows
#pragma unroll
  for (int mf = 0; mf < 2; ++mf) {
#pragma unroll
    for (int r = 0; r < 4; ++r) {
      int grow = mt * 128 + wm + mf * 16 + fq * 4 + r;
      if (grow < cnt) {
        int s = off + grow;
        int tokn = tok_of_row[s];
        float wgt = w_of_row[s];
        float* po = out + (size_t)tokn * HIDDEN + ns * 128 + fr;
#pragma unroll
        for (int nf = 0; nf < 8; ++nf)
          atomicAdd(po + nf * 16, acc[mf][nf][r] * wgt);
      }
    }
  }
}

extern "C" void kernel_launch(void* const* d_in, const int* in_sizes, int n_in,
                              void* d_out, int out_size, void* d_ws, size_t ws_size,
                              hipStream_t stream) {
  const float* hidden = (const float*)d_in[0];
  const float* topk_w = (const float*)d_in[1];
  const float* w1     = (const float*)d_in[2];
  const float* w2     = (const float*)d_in[3];
  const int*   tkidx  = (const int*)d_in[4];

  char* ws = (char*)d_ws;
  int*      offs       = (int*)ws;                       // 33 ints
  int*      tok_of_row = (int*)(ws + 1024);              // TA ints
  float*    w_of_row   = (float*)(ws + 1024 + 4 * TA);   // TA floats
  uint16_t* A_ws       = (uint16_t*)(ws + 131072);       // TA x 1408 bf16 (~23 MB)
  float*    out        = (float*)d_out;

  hipMemsetAsync(d_out, 0, (size_t)out_size * sizeof(float), stream);
  route_count<<<1, 256, 0, stream>>>(tkidx, offs);
  route_build<<<NUM_EXPERTS, 64, 0, stream>>>(tkidx, topk_w, offs, tok_of_row, w_of_row);
  moe_gemm1<<<dim3(HALFI / 64, 4, NUM_EXPERTS), 256, 0, stream>>>(hidden, w1, offs, tok_of_row, A_ws);
  moe_gemm2<<<dim3(HIDDEN / 128, 4, NUM_EXPERTS), 256, 0, stream>>>(A_ws, w2, offs, tok_of_row, w_of_row, out);
}